// Round 1
// baseline (270.319 us; speedup 1.0000x reference)
//
#include <hip/hip_runtime.h>

// B=16, S=8192, D=256, N=64, IDX=3, slot-norm softmax.
// Algebra: logits = (x·Q' + qb)/16 with Q' = queries@Wk;  out = (wsum·Wv^T)/denom + bv
// with wsum[b,:] = sum_s p3[b,s]·x[b,s,:], denom[b] = sum_s p3[b,s].
// => keys/values GEMMs eliminated; single streaming pass over x and mask.

#define B_ 16
#define S_ 8192
#define D_ 256
#define N_ 64
#define NEG_ (-9e15f)
#define LSTR 264  // LDS row stride in bf16 elems (256 + 8 pad, keeps 16B alignment)

typedef __attribute__((ext_vector_type(8))) short s8_t;   // 8 bf16 (4 VGPRs) MFMA frag
typedef __attribute__((ext_vector_type(4))) float f4_t;   // 4 fp32 MFMA acc
typedef unsigned int u32;
typedef unsigned short u16;

__device__ __forceinline__ u16 f2bf(float f) {
  u32 u = __builtin_bit_cast(u32, f);
  u += 0x7fffu + ((u >> 16) & 1u);   // RNE
  return (u16)(u >> 16);
}
__device__ __forceinline__ float bflo(u32 p) { return __builtin_bit_cast(float, p << 16); }
__device__ __forceinline__ float bfhi(u32 p) { return __builtin_bit_cast(float, p & 0xffff0000u); }

// ---- prep: Q'[n,d] = sum_e queries[n,e]*Wk[e,d] (bf16), qb[n] = queries[n]·bk ----
__global__ void prep_qk(const float* __restrict__ queries, const float* __restrict__ Wk,
                        const float* __restrict__ bk, u16* __restrict__ qp,
                        float* __restrict__ qb) {
  const int n = blockIdx.x, d = threadIdx.x;
  const float* q = &queries[n * D_];
  float acc = 0.f;
  for (int e = 0; e < D_; ++e) acc = fmaf(q[e], Wk[e * D_ + d], acc);  // Wk read coalesced
  qp[n * D_ + d] = f2bf(acc);
  if (d == 0) {
    float s = 0.f;
    for (int e = 0; e < D_; ++e) s = fmaf(q[e], bk[e], s);
    qb[n] = s;
  }
}

// ---- main: stream x+mask once; logits via bf16 MFMA; softmax over n; accumulate ----
__global__ __launch_bounds__(256, 2) void attn_main(
    const float* __restrict__ x, const int* __restrict__ mask,
    const u16* __restrict__ qp, const float* __restrict__ qb,
    float* __restrict__ wsum, float* __restrict__ denom, float* __restrict__ att) {
  __shared__ u16 q_lds[N_ * LSTR];   // Q' bf16, 33 KB
  __shared__ u16 in_lds[64 * LSTR];  // x tile bf16, 33 KB
  __shared__ u32 pm[4 * 64];         // mask bits: pm[p*64+s] = bits n=16p..16p+15

  const int t = threadIdx.x;
  const int lane = t & 63;
  const int w = t >> 6;        // wave 0..3 -> s rows 16w..16w+15
  const int c15 = lane & 15;   // MFMA col / A-row lane index
  const int g = lane >> 4;     // MFMA quad
  const int b = blockIdx.y;
  const int sbase = blockIdx.x * 256;  // 32 s-blocks x 4 tiles x 64 s

  // stage Q' into LDS (stride LSTR)
  {
    const int n = t >> 2, q = t & 3;
#pragma unroll
    for (int j = 0; j < 8; ++j)
      *(uint4*)&q_lds[n * LSTR + q * 64 + j * 8] = *(const uint4*)&qp[n * D_ + q * 64 + j * 8];
  }
  float qbv[4];
#pragma unroll
  for (int t4 = 0; t4 < 4; ++t4) qbv[t4] = qb[t4 * 16 + c15];

  f4_t wacc = {0.f, 0.f, 0.f, 0.f};  // lane owns d = lane*4..lane*4+3
  float dacc = 0.f;

  for (int tt = 0; tt < 4; ++tt) {
    const int s0 = sbase + tt * 64;
    __syncthreads();  // covers initial q_lds stage and prior-tile LDS readers
    // stage input tile fp32->bf16 (global reads: 64 lanes x 16B contiguous)
    {
      const int col = (t & 63) * 4;
#pragma unroll
      for (int it = 0; it < 16; ++it) {
        const int row = it * 4 + w;
        const float4 v = *(const float4*)&x[(((long)b * S_) + s0 + row) * D_ + col];
        uint2 h;
        h.x = (u32)f2bf(v.x) | ((u32)f2bf(v.y) << 16);
        h.y = (u32)f2bf(v.z) | ((u32)f2bf(v.w) << 16);
        *(uint2*)&in_lds[row * LSTR + col] = h;
      }
      // mask bits: wave reads one n-row of 64 consecutive ints per iter (coalesced)
      const int s = t & 63, p = t >> 6;
      const int* mrow = mask + ((long)b * N_ + p * 16) * S_ + s0 + s;
      u32 bits = 0;
#pragma unroll
      for (int i = 0; i < 16; ++i) bits |= (u32)(mrow[i * S_] != 0) << i;
      pm[p * 64 + s] = bits;
    }
    __syncthreads();

    // logits: D[srow=(g*4+r)][n=16*t4+c15] over K=256 in 8 chunks of 32
    f4_t acc[4] = {{0.f,0.f,0.f,0.f},{0.f,0.f,0.f,0.f},{0.f,0.f,0.f,0.f},{0.f,0.f,0.f,0.f}};
    const u16* arow = &in_lds[(16 * w + c15) * LSTR + g * 8];
    const u16* br0 = &q_lds[(0 + c15) * LSTR + g * 8];
    const u16* br1 = &q_lds[(16 + c15) * LSTR + g * 8];
    const u16* br2 = &q_lds[(32 + c15) * LSTR + g * 8];
    const u16* br3 = &q_lds[(48 + c15) * LSTR + g * 8];
#pragma unroll
    for (int c = 0; c < 8; ++c) {
      const s8_t a = *(const s8_t*)&arow[c * 32];
      acc[0] = __builtin_amdgcn_mfma_f32_16x16x32_bf16(a, *(const s8_t*)&br0[c * 32], acc[0], 0, 0, 0);
      acc[1] = __builtin_amdgcn_mfma_f32_16x16x32_bf16(a, *(const s8_t*)&br1[c * 32], acc[1], 0, 0, 0);
      acc[2] = __builtin_amdgcn_mfma_f32_16x16x32_bf16(a, *(const s8_t*)&br2[c * 32], acc[2], 0, 0, 0);
      acc[3] = __builtin_amdgcn_mfma_f32_16x16x32_bf16(a, *(const s8_t*)&br3[c * 32], acc[3], 0, 0, 0);
    }

    // softmax over n (64 slots = 4 tiles x 16 lanes of this 16-lane group)
    float unorm[4];
#pragma unroll
    for (int r = 0; r < 4; ++r) {
      const int sl = 16 * w + g * 4 + r;  // s-local of this (reg, quad)
      float lf[4];
#pragma unroll
      for (int t4 = 0; t4 < 4; ++t4)
        lf[t4] = ((pm[t4 * 64 + sl] >> c15) & 1) ? (acc[t4][r] + qbv[t4]) * 0.0625f : NEG_;
      float m = fmaxf(fmaxf(lf[0], lf[1]), fmaxf(lf[2], lf[3]));
      m = fmaxf(m, __shfl_xor(m, 1));
      m = fmaxf(m, __shfl_xor(m, 2));
      m = fmaxf(m, __shfl_xor(m, 4));
      m = fmaxf(m, __shfl_xor(m, 8));
      const float e0 = __expf(lf[0] - m);
      float sm = e0 + __expf(lf[1] - m) + __expf(lf[2] - m) + __expf(lf[3] - m);
      sm += __shfl_xor(sm, 1);
      sm += __shfl_xor(sm, 2);
      sm += __shfl_xor(sm, 4);
      sm += __shfl_xor(sm, 8);
      const float e3 = __shfl(e0, (lane & 48) | 3);  // n=IDX=3 lives at t4=0, c15==3
      unorm[r] = e3 / sm;                            // softmax-over-slots value, pre row-norm
    }
    if (c15 == 3) {  // 4 lanes x float4 = 16 consecutive floats per wave
      f4_t u = {unorm[0], unorm[1], unorm[2], unorm[3]};
      *(f4_t*)&att[(long)b * S_ + s0 + 16 * w + g * 4] = u;
    }
    // wsum += a_s * x[s,:] over this wave's 16 rows (bf16 from LDS, fp32 acc)
#pragma unroll
    for (int r = 0; r < 4; ++r) {
#pragma unroll
      for (int gg = 0; gg < 4; ++gg) {
        const float a_s = __shfl(unorm[r], gg * 16);  // row 16w+gg*4+r (group-uniform)
        const uint2 h = *(const uint2*)&in_lds[(16 * w + gg * 4 + r) * LSTR + lane * 4];
        wacc[0] = fmaf(a_s, bflo(h.x), wacc[0]);
        wacc[1] = fmaf(a_s, bfhi(h.x), wacc[1]);
        wacc[2] = fmaf(a_s, bflo(h.y), wacc[2]);
        wacc[3] = fmaf(a_s, bfhi(h.y), wacc[3]);
        dacc += a_s;
      }
    }
  }
#pragma unroll
  for (int j = 0; j < 4; ++j) atomicAdd(&wsum[b * D_ + lane * 4 + j], wacc[j]);
  if (lane == 0) atomicAdd(&denom[b], dacc);  // dacc is lane-uniform
}

// ---- finalize: out = (wsum·Wv^T)/denom + bv ; att *= 1/denom ----
__global__ void finalize_k(const float* __restrict__ wsum, const float* __restrict__ denom,
                           const float* __restrict__ Wv, const float* __restrict__ bv,
                           float* __restrict__ out, float* __restrict__ att) {
  __shared__ float wl[D_];
  const int b = blockIdx.x, t = threadIdx.x;
  wl[t] = wsum[b * D_ + t];
  __syncthreads();
  const float dn = denom[b];
  float o = 0.f;
  const float* wr = &Wv[t * D_];
  for (int e = 0; e < D_; ++e) o = fmaf(wl[e], wr[e], o);
  out[b * D_ + t] = o / dn + bv[t];
  const float inv = 1.0f / dn;
  for (int s = t; s < S_; s += 256) att[(long)b * S_ + s] *= inv;
}

extern "C" void kernel_launch(void* const* d_in, const int* in_sizes, int n_in,
                              void* d_out, int out_size, void* d_ws, size_t ws_size,
                              hipStream_t stream) {
  const float* x = (const float*)d_in[0];        // [16,8192,256]
  const int* mask = (const int*)d_in[1];         // [16,64,8192]
  const float* Wv = (const float*)d_in[2];
  const float* bv = (const float*)d_in[3];
  const float* Wk = (const float*)d_in[4];
  const float* bk = (const float*)d_in[5];
  const float* queries = (const float*)d_in[6];  // [64,256]

  char* ws = (char*)d_ws;                 // layout (~49.5 KB total):
  u16* qp = (u16*)ws;                     // [0, 32768)  Q' bf16
  float* qb = (float*)(ws + 32768);       // [32768, 33024)
  float* wsum = (float*)(ws + 33024);     // [33024, 49408)  16x256 f32
  float* denom = (float*)(ws + 49408);    // [49408, 49472)  16 f32
  float* out = (float*)d_out;             // 16*256
  float* att = out + B_ * D_;             // 16*8192

  hipMemsetAsync(wsum, 0, 16384 + 64, stream);  // zero wsum+denom (ws is poisoned 0xAA)
  prep_qk<<<N_, D_, 0, stream>>>(queries, Wk, bk, qp, qb);
  attn_main<<<dim3(32, B_), 256, 0, stream>>>(x, mask, qp, qb, wsum, denom, att);
  finalize_k<<<B_, D_, 0, stream>>>(wsum, denom, Wv, bv, out, att);
}